// Round 1
// baseline (2130.282 us; speedup 1.0000x reference)
//
#include <hip/hip_runtime.h>
#include <hip/hip_bf16.h>
#include <math.h>

#define T_ 8
#define N_ 2048
#define F_ 128
#define H_ 4

// ---------------------------------------------------------------------------
// Kernel 1: th[h,t,n,g] = sum_f x[t,n,f] * W[h,f,g]
// grid = H*T*(N/64), block = 256. Tile: 64 rows x 128 cols, per-thread 4x8.
// ---------------------------------------------------------------------------
__global__ __launch_bounds__(256) void k_th(const float* __restrict__ x,
                                            const float* __restrict__ W,
                                            float* __restrict__ th) {
    __shared__ float xs[64][132];

    const int b = blockIdx.x;
    const int h = b / (T_ * (N_ / 64));
    const int rem = b % (T_ * (N_ / 64));
    const int t = rem / (N_ / 64);
    const int n0 = (rem % (N_ / 64)) * 64;
    const int tid = threadIdx.x;

    // stage x tile: rows n0..n0+63, all 128 f
    {
        const int r = tid >> 2;               // 0..63
        const int c0 = (tid & 3) * 32;        // 0,32,64,96
        const float4* src = reinterpret_cast<const float4*>(
            x + ((size_t)t * N_ + (n0 + r)) * F_ + c0);
        #pragma unroll
        for (int u = 0; u < 8; ++u) {
            float4 v = src[u];
            int c = c0 + u * 4;
            xs[r][c + 0] = v.x; xs[r][c + 1] = v.y;
            xs[r][c + 2] = v.z; xs[r][c + 3] = v.w;
        }
    }
    __syncthreads();

    const int rowg = tid >> 4;    // 0..15 -> rows 4*rowg..+3
    const int colg = tid & 15;    // cols colg*8..+7
    const int r0 = rowg * 4;
    const int c0 = colg * 8;

    float acc[4][8];
    #pragma unroll
    for (int i = 0; i < 4; ++i)
        #pragma unroll
        for (int j = 0; j < 8; ++j) acc[i][j] = 0.f;

    const float* Wb = W + (size_t)h * F_ * F_ + c0;
    #pragma unroll 4
    for (int f = 0; f < F_; ++f) {
        const float4 w0 = *reinterpret_cast<const float4*>(Wb + (size_t)f * F_);
        const float4 w1 = *reinterpret_cast<const float4*>(Wb + (size_t)f * F_ + 4);
        float a[4];
        #pragma unroll
        for (int i = 0; i < 4; ++i) a[i] = xs[r0 + i][f];
        #pragma unroll
        for (int i = 0; i < 4; ++i) {
            acc[i][0] += a[i] * w0.x; acc[i][1] += a[i] * w0.y;
            acc[i][2] += a[i] * w0.z; acc[i][3] += a[i] * w0.w;
            acc[i][4] += a[i] * w1.x; acc[i][5] += a[i] * w1.y;
            acc[i][6] += a[i] * w1.z; acc[i][7] += a[i] * w1.w;
        }
    }

    float* dst = th + (((size_t)h * T_ + t) * N_ + n0) * F_ + c0;
    #pragma unroll
    for (int i = 0; i < 4; ++i) {
        float4 v0 = {acc[i][0], acc[i][1], acc[i][2], acc[i][3]};
        float4 v1 = {acc[i][4], acc[i][5], acc[i][6], acc[i][7]};
        *reinterpret_cast<float4*>(dst + (size_t)(r0 + i) * F_) = v0;
        *reinterpret_cast<float4*>(dst + (size_t)(r0 + i) * F_ + 4) = v1;
    }
}

// ---------------------------------------------------------------------------
// Kernel 2: flash attention per (h, 32-row q tile); t-loop inside block.
// s[h,n,f] = (1/T) * sum_t softmax_m(q[h,n,:]·th[h,t,m,:]) @ th[h,t,:,:]
// grid = H*(N/32), block = 256 (16 rowg x 16 colg; 2 rows x {4 score / 8 out} cols)
// K tile LDS is XOR-swizzled on the g-float4 index by (row>>3) so the
// scores-side reads (row-per-lane, same g) are 2-way (free).
// ---------------------------------------------------------------------------
__global__ __launch_bounds__(256) void k_attn(const float* __restrict__ th,
                                              float* __restrict__ s) {
    __shared__ float qs[32][132];
    __shared__ float ks[64][132];
    __shared__ float ps[32][68];

    const int b = blockIdx.x;
    const int h = b / (N_ / 32);
    const int n0 = (b % (N_ / 32)) * 32;
    const int tid = threadIdx.x;
    const int rowg = tid >> 4;     // 0..15
    const int colg = tid & 15;     // 0..15
    const int r0 = rowg * 2;       // 2 q-rows per thread
    const int cs0 = colg * 4;      // score cols
    const int co0 = colg * 8;      // output cols

    const float* thh = th + (size_t)h * T_ * N_ * F_;

    // stage Q tile = th[h, T-1, n0..n0+31, :]
    {
        const int r = tid >> 3;               // 0..31
        const int c0 = (tid & 7) * 16;
        const float4* src = reinterpret_cast<const float4*>(
            thh + ((size_t)(T_ - 1) * N_ + (n0 + r)) * F_ + c0);
        #pragma unroll
        for (int u = 0; u < 4; ++u) {
            float4 v = src[u];
            int c = c0 + u * 4;
            qs[r][c + 0] = v.x; qs[r][c + 1] = v.y;
            qs[r][c + 2] = v.z; qs[r][c + 3] = v.w;
        }
    }

    float sacc[2][8];
    #pragma unroll
    for (int i = 0; i < 2; ++i)
        #pragma unroll
        for (int j = 0; j < 8; ++j) sacc[i][j] = 0.f;

    for (int t = 0; t < T_; ++t) {
        const float* tht = thh + (size_t)t * N_ * F_;
        float mr[2] = {-3e38f, -3e38f};
        float lr[2] = {0.f, 0.f};
        float o[2][8];
        #pragma unroll
        for (int i = 0; i < 2; ++i)
            #pragma unroll
            for (int j = 0; j < 8; ++j) o[i][j] = 0.f;

        for (int mt = 0; mt < N_ / 64; ++mt) {
            __syncthreads();   // protect ks/ps from previous iteration readers
            // stage K(=V) tile rows mt*64..+63, g-f4 swizzled by (row>>3)
            {
                const int r = tid >> 2;            // 0..63
                const int g0 = (tid & 3) * 32;
                const float4* src = reinterpret_cast<const float4*>(
                    tht + (size_t)(mt * 64 + r) * F_ + g0);
                const int sw = (r >> 3) & 7;
                #pragma unroll
                for (int u = 0; u < 8; ++u) {
                    float4 v = src[u];
                    const int st = (((g0 >> 2) + u) ^ sw) * 4;
                    ks[r][st + 0] = v.x; ks[r][st + 1] = v.y;
                    ks[r][st + 2] = v.z; ks[r][st + 3] = v.w;
                }
            }
            __syncthreads();

            // scores S[2][4] = q-rows · K-rows
            float sc[2][4] = {{0.f, 0.f, 0.f, 0.f}, {0.f, 0.f, 0.f, 0.f}};
            #pragma unroll 8
            for (int kk = 0; kk < 32; ++kk) {
                const float4 a0 = *reinterpret_cast<const float4*>(&qs[r0][kk * 4]);
                const float4 a1 = *reinterpret_cast<const float4*>(&qs[r0 + 1][kk * 4]);
                #pragma unroll
                for (int j = 0; j < 4; ++j) {
                    const int c = cs0 + j;
                    const float4 bv = *reinterpret_cast<const float4*>(
                        &ks[c][(kk ^ (c >> 3)) * 4]);
                    sc[0][j] += a0.x * bv.x + a0.y * bv.y + a0.z * bv.z + a0.w * bv.w;
                    sc[1][j] += a1.x * bv.x + a1.y * bv.y + a1.z * bv.z + a1.w * bv.w;
                }
            }

            // online softmax update (rows shared by the 16 colg lanes)
            float rmax[2];
            #pragma unroll
            for (int i = 0; i < 2; ++i)
                rmax[i] = fmaxf(fmaxf(sc[i][0], sc[i][1]), fmaxf(sc[i][2], sc[i][3]));
            #pragma unroll
            for (int off = 8; off > 0; off >>= 1) {
                rmax[0] = fmaxf(rmax[0], __shfl_xor(rmax[0], off, 16));
                rmax[1] = fmaxf(rmax[1], __shfl_xor(rmax[1], off, 16));
            }

            float p[2][4];
            #pragma unroll
            for (int i = 0; i < 2; ++i) {
                const float mn = fmaxf(mr[i], rmax[i]);
                const float alpha = expf(mr[i] - mn);
                #pragma unroll
                for (int j = 0; j < 4; ++j) p[i][j] = expf(sc[i][j] - mn);
                float rs = (p[i][0] + p[i][1]) + (p[i][2] + p[i][3]);
                #pragma unroll
                for (int off = 8; off > 0; off >>= 1)
                    rs += __shfl_xor(rs, off, 16);
                lr[i] = lr[i] * alpha + rs;
                mr[i] = mn;
                #pragma unroll
                for (int j = 0; j < 8; ++j) o[i][j] *= alpha;
            }

            // publish P tile
            #pragma unroll
            for (int i = 0; i < 2; ++i)
                #pragma unroll
                for (int j = 0; j < 4; ++j)
                    ps[r0 + i][cs0 + j] = p[i][j];
            __syncthreads();

            // PV: o[i][0..7] += sum_k p[i][k] * V[k][co0..co0+7]
            #pragma unroll 4
            for (int k = 0; k < 64; ++k) {
                const float pa0 = ps[r0][k];
                const float pa1 = ps[r0 + 1][k];
                const int sw = k >> 3;
                const float4 v0 = *reinterpret_cast<const float4*>(
                    &ks[k][((co0 >> 2) ^ sw) * 4]);
                const float4 v1 = *reinterpret_cast<const float4*>(
                    &ks[k][(((co0 >> 2) + 1) ^ sw) * 4]);
                o[0][0] += pa0 * v0.x; o[0][1] += pa0 * v0.y;
                o[0][2] += pa0 * v0.z; o[0][3] += pa0 * v0.w;
                o[0][4] += pa0 * v1.x; o[0][5] += pa0 * v1.y;
                o[0][6] += pa0 * v1.z; o[0][7] += pa0 * v1.w;
                o[1][0] += pa1 * v0.x; o[1][1] += pa1 * v0.y;
                o[1][2] += pa1 * v0.z; o[1][3] += pa1 * v0.w;
                o[1][4] += pa1 * v1.x; o[1][5] += pa1 * v1.y;
                o[1][6] += pa1 * v1.z; o[1][7] += pa1 * v1.w;
            }
        }

        // fold this t's normalized output into sacc
        #pragma unroll
        for (int i = 0; i < 2; ++i) {
            const float inv = 1.f / lr[i];
            #pragma unroll
            for (int j = 0; j < 8; ++j) sacc[i][j] += o[i][j] * inv;
        }
    }

    // write s[h, n0+r0+i, co0..co0+7], including the /seq_len
    float* sd = s + ((size_t)h * N_ + n0) * F_ + co0;
    const float qsc = 1.f / (float)T_;
    #pragma unroll
    for (int i = 0; i < 2; ++i) {
        float4 v0 = {sacc[i][0] * qsc, sacc[i][1] * qsc, sacc[i][2] * qsc, sacc[i][3] * qsc};
        float4 v1 = {sacc[i][4] * qsc, sacc[i][5] * qsc, sacc[i][6] * qsc, sacc[i][7] * qsc};
        *reinterpret_cast<float4*>(sd + (size_t)(r0 + i) * F_) = v0;
        *reinterpret_cast<float4*>(sd + (size_t)(r0 + i) * F_ + 4) = v1;
    }
}

// ---------------------------------------------------------------------------
// Kernel 3: out[n,f] = mean_h elu(s[h,n,f])
// ---------------------------------------------------------------------------
__global__ __launch_bounds__(256) void k_out(const float* __restrict__ s,
                                             float* __restrict__ out) {
    const int i = blockIdx.x * blockDim.x + threadIdx.x;
    if (i >= (N_ * F_) / 4) return;
    const float4* s4 = reinterpret_cast<const float4*>(s);
    float4 acc = {0.f, 0.f, 0.f, 0.f};
    #pragma unroll
    for (int h = 0; h < H_; ++h) {
        float4 v = s4[(size_t)h * (N_ * F_ / 4) + i];
        acc.x += (v.x > 0.f) ? v.x : (expf(v.x) - 1.f);
        acc.y += (v.y > 0.f) ? v.y : (expf(v.y) - 1.f);
        acc.z += (v.z > 0.f) ? v.z : (expf(v.z) - 1.f);
        acc.w += (v.w > 0.f) ? v.w : (expf(v.w) - 1.f);
    }
    const float q = 1.f / (float)H_;
    float4 r = {acc.x * q, acc.y * q, acc.z * q, acc.w * q};
    reinterpret_cast<float4*>(out)[i] = r;
}

extern "C" void kernel_launch(void* const* d_in, const int* in_sizes, int n_in,
                              void* d_out, int out_size, void* d_ws, size_t ws_size,
                              hipStream_t stream) {
    const float* x = (const float*)d_in[0];   // (T, N, F)
    const float* W = (const float*)d_in[1];   // (H, F, F)
    float* out = (float*)d_out;               // (N, F)

    // workspace: th (H*T*N*F floats = 32 MB) then s (H*N*F floats = 4 MB)
    float* th = (float*)d_ws;
    float* s = th + (size_t)H_ * T_ * N_ * F_;

    k_th<<<H_ * T_ * (N_ / 64), 256, 0, stream>>>(x, W, th);
    k_attn<<<H_ * (N_ / 32), 256, 0, stream>>>(th, s);
    k_out<<<(N_ * F_ / 4 + 255) / 256, 256, 0, stream>>>(s, out);
}

// Round 2
// 204.707 us; speedup vs baseline: 10.4065x; 10.4065x over previous
//
#include <hip/hip_runtime.h>
#include <hip/hip_bf16.h>
#include <math.h>

#define T_ 8
#define N_ 2048
#define F_ 128
#define H_ 4

typedef unsigned int u32;
typedef unsigned short ushort_t;
typedef float f32x16 __attribute__((ext_vector_type(16)));
typedef short bf16x8 __attribute__((ext_vector_type(8)));
typedef u32 u32x4 __attribute__((ext_vector_type(4)));

static __device__ __forceinline__ ushort_t f2bf_rtn(float v) {
    u32 u = __float_as_uint(v);
    u32 r = (u + 0x7fffu + ((u >> 16) & 1u)) >> 16;
    return (ushort_t)r;
}
static __device__ __forceinline__ float bf2f(ushort_t h) {
    return __uint_as_float(((u32)h) << 16);
}

// ---------------------------------------------------------------------------
// Kernel 1: th = x @ W per (h,t); writes bf16 hi, bf16 lo (residual), and a
// 32-row-chunked transposed hi copy th_hiT[h][t][n/32][g][32] for V staging.
// grid = H*T*(N/64), block=256, per-thread 4x8 tile.
// ---------------------------------------------------------------------------
__global__ __launch_bounds__(256) void k_th(const float* __restrict__ x,
                                            const float* __restrict__ W,
                                            ushort_t* __restrict__ th_hi,
                                            ushort_t* __restrict__ th_lo,
                                            ushort_t* __restrict__ th_hiT) {
    __shared__ float xs[64][132];

    const int b = blockIdx.x;
    const int h = b / (T_ * (N_ / 64));
    const int rem = b % (T_ * (N_ / 64));
    const int t = rem / (N_ / 64);
    const int n0 = (rem % (N_ / 64)) * 64;
    const int tid = threadIdx.x;

    {
        const int r = tid >> 2;
        const int c0 = (tid & 3) * 32;
        const float4* src = reinterpret_cast<const float4*>(
            x + ((size_t)t * N_ + (n0 + r)) * F_ + c0);
        #pragma unroll
        for (int u = 0; u < 8; ++u) {
            float4 v = src[u];
            int c = c0 + u * 4;
            xs[r][c + 0] = v.x; xs[r][c + 1] = v.y;
            xs[r][c + 2] = v.z; xs[r][c + 3] = v.w;
        }
    }
    __syncthreads();

    const int rowg = tid >> 4;
    const int colg = tid & 15;
    const int r0 = rowg * 4;
    const int c0 = colg * 8;

    float acc[4][8];
    #pragma unroll
    for (int i = 0; i < 4; ++i)
        #pragma unroll
        for (int j = 0; j < 8; ++j) acc[i][j] = 0.f;

    const float* Wb = W + (size_t)h * F_ * F_ + c0;
    #pragma unroll 4
    for (int f = 0; f < F_; ++f) {
        const float4 w0 = *reinterpret_cast<const float4*>(Wb + (size_t)f * F_);
        const float4 w1 = *reinterpret_cast<const float4*>(Wb + (size_t)f * F_ + 4);
        float a[4];
        #pragma unroll
        for (int i = 0; i < 4; ++i) a[i] = xs[r0 + i][f];
        #pragma unroll
        for (int i = 0; i < 4; ++i) {
            acc[i][0] += a[i] * w0.x; acc[i][1] += a[i] * w0.y;
            acc[i][2] += a[i] * w0.z; acc[i][3] += a[i] * w0.w;
            acc[i][4] += a[i] * w1.x; acc[i][5] += a[i] * w1.y;
            acc[i][6] += a[i] * w1.z; acc[i][7] += a[i] * w1.w;
        }
    }

    ushort_t hiv[4][8], lov[4][8];
    #pragma unroll
    for (int i = 0; i < 4; ++i)
        #pragma unroll
        for (int j = 0; j < 8; ++j) {
            float v = acc[i][j];
            ushort_t hh = f2bf_rtn(v);
            hiv[i][j] = hh;
            lov[i][j] = f2bf_rtn(v - bf2f(hh));
        }

    const size_t rowbase = (((size_t)h * T_ + t) * N_ + n0);
    #pragma unroll
    for (int i = 0; i < 4; ++i) {
        uint4 hv = *reinterpret_cast<uint4*>(&hiv[i][0]);
        uint4 lv = *reinterpret_cast<uint4*>(&lov[i][0]);
        *reinterpret_cast<uint4*>(th_hi + (rowbase + r0 + i) * F_ + c0) = hv;
        *reinterpret_cast<uint4*>(th_lo + (rowbase + r0 + i) * F_ + c0) = lv;
    }

    // transposed chunked hi copy: [h][t][nc][g][32]
    {
        const int nc = (n0 + r0) >> 5;
        const int nin = r0 & 31;
        ushort_t* base = th_hiT + ((((size_t)h * T_ + t) * (N_ / 32) + nc) * F_) * 32;
        #pragma unroll
        for (int j = 0; j < 8; ++j) {
            u32 p0 = (u32)hiv[0][j] | ((u32)hiv[1][j] << 16);
            u32 p1 = (u32)hiv[2][j] | ((u32)hiv[3][j] << 16);
            u32* dst = reinterpret_cast<u32*>(base + (size_t)(c0 + j) * 32 + nin);
            dst[0] = p0;
            dst[1] = p1;
        }
    }
}

// ---------------------------------------------------------------------------
// Kernel 2: MFMA flash attention, S^T = K*Q^T orientation.
// grid = 512 = (h,t,qtile); block = 256 (4 waves x 32 q-cols each).
// m-tile = 32 keys; K hi/lo LDS XOR-swizzled; V tile fused-row layout.
// Writes s_part[h][t][n][g] (f32, un-normalized by T).
// ---------------------------------------------------------------------------
__global__ __launch_bounds__(256, 2) void k_attn(const ushort_t* __restrict__ th_hi,
                                                 const ushort_t* __restrict__ th_lo,
                                                 const ushort_t* __restrict__ th_hiT,
                                                 float* __restrict__ s_part) {
    __shared__ ushort_t kh[2][32][128];
    __shared__ ushort_t kl[2][32][128];
    __shared__ ushort_t vt[2][64][72];   // row r: g=2r (m 0..31) | g=2r+1 (m 0..31), +8 pad

    const int tid = threadIdx.x;
    const int lane = tid & 63;
    const int w = tid >> 6;
    const int l31 = lane & 31;
    const int h5 = lane >> 5;

    // XCD-grouping swizzle: 16 q-siblings (same h,t) land on one XCD
    const int vid = ((blockIdx.x & 7) << 6) | (blockIdx.x >> 3);
    const int h = vid >> 7;
    const int t = (vid >> 4) & 7;
    const int qt = vid & 15;
    const int q0 = qt * 128 + w * 32;

    const size_t ht = (size_t)h * T_ + t;
    const ushort_t* Khi_g = th_hi + ht * (N_ * F_);
    const ushort_t* Klo_g = th_lo + ht * (N_ * F_);
    const ushort_t* VT_g  = th_hiT + ht * ((N_ / 32) * F_ * 32);
    const ushort_t* Qhi_g = th_hi + ((size_t)h * T_ + (T_ - 1)) * (N_ * F_);
    const ushort_t* Qlo_g = th_lo + ((size_t)h * T_ + (T_ - 1)) * (N_ * F_);

    // Q fragments in registers: lane -> q = q0+l31, f = ks*16 + h5*8 + j
    bf16x8 qh[8], ql[8];
    {
        const ushort_t* qrh = Qhi_g + (size_t)(q0 + l31) * F_ + h5 * 8;
        const ushort_t* qrl = Qlo_g + (size_t)(q0 + l31) * F_ + h5 * 8;
        #pragma unroll
        for (int ks = 0; ks < 8; ++ks) {
            qh[ks] = *reinterpret_cast<const bf16x8*>(qrh + ks * 16);
            ql[ks] = *reinterpret_cast<const bf16x8*>(qrl + ks * 16);
        }
    }

    const int sm = tid >> 3;            // staging: K row 0..31
    const int sfc = tid & 7;            // staging: 16-elem f chunk
    const int ssx = sm & 15;
    const int sg = tid >> 1;            // staging: V g-row 0..127
    const int smh = (tid & 1) * 16;     // staging: V m half

    // prologue: stage tile 0 into buffer 0
    {
        const size_t grow = (size_t)(0 * 32 + sm) * F_ + sfc * 16;
        uint4 a0 = *reinterpret_cast<const uint4*>(Khi_g + grow);
        uint4 a1 = *reinterpret_cast<const uint4*>(Khi_g + grow + 8);
        uint4 b0 = *reinterpret_cast<const uint4*>(Klo_g + grow);
        uint4 b1 = *reinterpret_cast<const uint4*>(Klo_g + grow + 8);
        const ushort_t* vsrc = VT_g + (size_t)sg * 32 + smh;
        uint4 v0 = *reinterpret_cast<const uint4*>(vsrc);
        uint4 v1 = *reinterpret_cast<const uint4*>(vsrc + 8);
        *reinterpret_cast<uint4*>(&kh[0][sm][((sfc * 2 + 0) ^ ssx) * 8]) = a0;
        *reinterpret_cast<uint4*>(&kh[0][sm][((sfc * 2 + 1) ^ ssx) * 8]) = a1;
        *reinterpret_cast<uint4*>(&kl[0][sm][((sfc * 2 + 0) ^ ssx) * 8]) = b0;
        *reinterpret_cast<uint4*>(&kl[0][sm][((sfc * 2 + 1) ^ ssx) * 8]) = b1;
        ushort_t* vdst = &vt[0][sg >> 1][(sg & 1) * 32 + smh];
        *reinterpret_cast<uint4*>(vdst) = v0;
        *reinterpret_cast<uint4*>(vdst + 8) = v1;
    }
    __syncthreads();

    f32x16 o2[4];
    #pragma unroll
    for (int gs = 0; gs < 4; ++gs)
        #pragma unroll
        for (int r = 0; r < 16; ++r) o2[gs][r] = 0.f;

    float m_run = -3e38f, l_run = 0.f;
    const float CL2 = 1.4426950408889634f;

    for (int mt = 0; mt < N_ / 32; ++mt) {
        const int cur = mt & 1;
        const bool more = (mt + 1) < (N_ / 32);

        // T14: issue next-tile global loads before compute
        uint4 na0, na1, nb0, nb1, nv0, nv1;
        if (more) {
            const size_t grow = (size_t)((mt + 1) * 32 + sm) * F_ + sfc * 16;
            na0 = *reinterpret_cast<const uint4*>(Khi_g + grow);
            na1 = *reinterpret_cast<const uint4*>(Khi_g + grow + 8);
            nb0 = *reinterpret_cast<const uint4*>(Klo_g + grow);
            nb1 = *reinterpret_cast<const uint4*>(Klo_g + grow + 8);
            const ushort_t* vsrc = VT_g + (size_t)(mt + 1) * (F_ * 32) + (size_t)sg * 32 + smh;
            nv0 = *reinterpret_cast<const uint4*>(vsrc);
            nv1 = *reinterpret_cast<const uint4*>(vsrc + 8);
        }

        // ---- scores: S^T[m][q] via 3-term hi/lo split --------------------
        f32x16 S;
        #pragma unroll
        for (int r = 0; r < 16; ++r) S[r] = 0.f;
        #pragma unroll
        for (int ks = 0; ks < 8; ++ks) {
            const int grp = ((ks * 2 + h5) ^ (l31 & 15)) * 8;
            bf16x8 ah = *reinterpret_cast<const bf16x8*>(&kh[cur][l31][grp]);
            bf16x8 al = *reinterpret_cast<const bf16x8*>(&kl[cur][l31][grp]);
            S = __builtin_amdgcn_mfma_f32_32x32x16_bf16(ah, qh[ks], S, 0, 0, 0);
            S = __builtin_amdgcn_mfma_f32_32x32x16_bf16(ah, ql[ks], S, 0, 0, 0);
            S = __builtin_amdgcn_mfma_f32_32x32x16_bf16(al, qh[ks], S, 0, 0, 0);
        }

        // ---- online softmax: per-lane q-column stats ---------------------
        float tm = S[0];
        #pragma unroll
        for (int r = 1; r < 16; ++r) tm = fmaxf(tm, S[r]);
        tm = fmaxf(tm, __shfl_xor(tm, 32));
        const float Mn = fmaxf(m_run, tm);
        const float alpha = exp2f((m_run - Mn) * CL2);
        const float mc = Mn * CL2;
        float p[16];
        float ts = 0.f;
        #pragma unroll
        for (int r = 0; r < 16; ++r) {
            p[r] = exp2f(S[r] * CL2 - mc);
            ts += p[r];
        }
        ts += __shfl_xor(ts, 32);
        l_run = l_run * alpha + ts;
        m_run = Mn;
        #pragma unroll
        for (int gs = 0; gs < 4; ++gs)
            #pragma unroll
            for (int r = 0; r < 16; ++r) o2[gs][r] *= alpha;

        // ---- pack P^T fragments in-register (cvt_pk + half-wave swap) ----
        u32 pk[8], xk[8];
        #pragma unroll
        for (int c = 0; c < 8; ++c) {
            asm("v_cvt_pk_bf16_f32 %0, %1, %2" : "=v"(pk[c]) : "v"(p[2 * c]), "v"(p[2 * c + 1]));
        }
        #pragma unroll
        for (int c = 0; c < 8; ++c) xk[c] = (u32)__shfl_xor((int)pk[c], 32);

        u32x4 t0, t1;
        t0.x = h5 ? xk[2] : pk[0];
        t0.y = h5 ? xk[3] : pk[1];
        t0.z = h5 ? pk[2] : xk[0];
        t0.w = h5 ? pk[3] : xk[1];
        t1.x = h5 ? xk[6] : pk[4];
        t1.y = h5 ? xk[7] : pk[5];
        t1.z = h5 ? pk[6] : xk[4];
        t1.w = h5 ? pk[7] : xk[5];
        bf16x8 pb0 = __builtin_bit_cast(bf16x8, t0);
        bf16x8 pb1 = __builtin_bit_cast(bf16x8, t1);

        // ---- PV: out^T[g][q] += V^T * P^T --------------------------------
        #pragma unroll
        for (int gs = 0; gs < 4; ++gs) {
            const int g = gs * 32 + l31;
            const ushort_t* vrow = &vt[cur][g >> 1][(g & 1) * 32];
            bf16x8 v0 = *reinterpret_cast<const bf16x8*>(vrow + h5 * 8);
            bf16x8 v1 = *reinterpret_cast<const bf16x8*>(vrow + 16 + h5 * 8);
            o2[gs] = __builtin_amdgcn_mfma_f32_32x32x16_bf16(v0, pb0, o2[gs], 0, 0, 0);
            o2[gs] = __builtin_amdgcn_mfma_f32_32x32x16_bf16(v1, pb1, o2[gs], 0, 0, 0);
        }

        // ---- write next tile into the other buffer -----------------------
        if (more) {
            const int nb = cur ^ 1;
            *reinterpret_cast<uint4*>(&kh[nb][sm][((sfc * 2 + 0) ^ ssx) * 8]) = na0;
            *reinterpret_cast<uint4*>(&kh[nb][sm][((sfc * 2 + 1) ^ ssx) * 8]) = na1;
            *reinterpret_cast<uint4*>(&kl[nb][sm][((sfc * 2 + 0) ^ ssx) * 8]) = nb0;
            *reinterpret_cast<uint4*>(&kl[nb][sm][((sfc * 2 + 1) ^ ssx) * 8]) = nb1;
            ushort_t* vdst = &vt[nb][sg >> 1][(sg & 1) * 32 + smh];
            *reinterpret_cast<uint4*>(vdst) = nv0;
            *reinterpret_cast<uint4*>(vdst + 8) = nv1;
        }
        __syncthreads();
    }

    // epilogue: normalize and scatter-store out^T
    const float inv = 1.f / l_run;
    float* dst = s_part + (ht * N_ + (q0 + l31)) * F_;
    #pragma unroll
    for (int gs = 0; gs < 4; ++gs)
        #pragma unroll
        for (int r = 0; r < 16; ++r) {
            const int g = gs * 32 + (r & 3) + 8 * (r >> 2) + 4 * h5;
            dst[g] = o2[gs][r] * inv;
        }
}

// ---------------------------------------------------------------------------
// Kernel 3: out[n,g] = mean_h elu( (1/T) * sum_t s_part[h][t][n][g] )
// ---------------------------------------------------------------------------
__global__ __launch_bounds__(256) void k_out(const float* __restrict__ s_part,
                                             float* __restrict__ out) {
    const int i = blockIdx.x * blockDim.x + threadIdx.x;
    if (i >= (N_ * F_) / 4) return;
    const float4* sp = reinterpret_cast<const float4*>(s_part);
    float4 acc = {0.f, 0.f, 0.f, 0.f};
    const float invT = 1.f / (float)T_;
    #pragma unroll
    for (int h = 0; h < H_; ++h) {
        float4 hs = {0.f, 0.f, 0.f, 0.f};
        #pragma unroll
        for (int t = 0; t < T_; ++t) {
            float4 v = sp[(size_t)(h * T_ + t) * (N_ * F_ / 4) + i];
            hs.x += v.x; hs.y += v.y; hs.z += v.z; hs.w += v.w;
        }
        float ex = hs.x * invT, ey = hs.y * invT, ez = hs.z * invT, ew = hs.w * invT;
        acc.x += (ex > 0.f) ? ex : (expf(ex) - 1.f);
        acc.y += (ey > 0.f) ? ey : (expf(ey) - 1.f);
        acc.z += (ez > 0.f) ? ez : (expf(ez) - 1.f);
        acc.w += (ew > 0.f) ? ew : (expf(ew) - 1.f);
    }
    const float q = 1.f / (float)H_;
    float4 r = {acc.x * q, acc.y * q, acc.z * q, acc.w * q};
    reinterpret_cast<float4*>(out)[i] = r;
}

extern "C" void kernel_launch(void* const* d_in, const int* in_sizes, int n_in,
                              void* d_out, int out_size, void* d_ws, size_t ws_size,
                              hipStream_t stream) {
    const float* x = (const float*)d_in[0];   // (T, N, F)
    const float* W = (const float*)d_in[1];   // (H, F, F)
    float* out = (float*)d_out;               // (N, F)

    // ws layout: th_hi 16MB | th_lo 16MB | th_hiT 16MB | s_part 32MB  (80MB)
    const size_t TH_ELEMS = (size_t)H_ * T_ * N_ * F_;   // 8,388,608
    ushort_t* th_hi = (ushort_t*)d_ws;
    ushort_t* th_lo = th_hi + TH_ELEMS;
    ushort_t* th_hiT = th_lo + TH_ELEMS;
    float* s_part = (float*)(th_hiT + TH_ELEMS);

    k_th<<<H_ * T_ * (N_ / 64), 256, 0, stream>>>(x, W, th_hi, th_lo, th_hiT);
    k_attn<<<512, 256, 0, stream>>>(th_hi, th_lo, th_hiT, s_part);
    k_out<<<(N_ * F_ / 4 + 255) / 256, 256, 0, stream>>>(s_part, out);
}

// Round 4
// 173.417 us; speedup vs baseline: 12.2841x; 1.1804x over previous
//
#include <hip/hip_runtime.h>
#include <hip/hip_bf16.h>
#include <math.h>

#define T_ 8
#define N_ 2048
#define F_ 128
#define H_ 4
#define NT_ (N_ / 32)   // 64 key tiles per (h,t)

typedef unsigned int u32;
typedef unsigned short ushort_t;
typedef float f32x16 __attribute__((ext_vector_type(16)));
typedef _Float16 f16x8 __attribute__((ext_vector_type(8)));
typedef u32 u32x4 __attribute__((ext_vector_type(4)));

// ---------------------------------------------------------------------------
// Kernel 1: th = x @ W per (h,t) in fp32; writes fp16 hi, fp16 lo (residual),
// and a 32-row-chunked transposed hi copy th_hiT[h][t][n/32][g][32].
// grid = H*T*(N/64), block=256, per-thread 4x8 tile.
// ---------------------------------------------------------------------------
__global__ __launch_bounds__(256) void k_th(const float* __restrict__ x,
                                            const float* __restrict__ W,
                                            ushort_t* __restrict__ th_hi,
                                            ushort_t* __restrict__ th_lo,
                                            ushort_t* __restrict__ th_hiT) {
    __shared__ float xs[64][132];

    const int b = blockIdx.x;
    const int h = b / (T_ * (N_ / 64));
    const int rem = b % (T_ * (N_ / 64));
    const int t = rem / (N_ / 64);
    const int n0 = (rem % (N_ / 64)) * 64;
    const int tid = threadIdx.x;

    {
        const int r = tid >> 2;
        const int c0 = (tid & 3) * 32;
        const float4* src = reinterpret_cast<const float4*>(
            x + ((size_t)t * N_ + (n0 + r)) * F_ + c0);
        #pragma unroll
        for (int u = 0; u < 8; ++u) {
            float4 v = src[u];
            int c = c0 + u * 4;
            xs[r][c + 0] = v.x; xs[r][c + 1] = v.y;
            xs[r][c + 2] = v.z; xs[r][c + 3] = v.w;
        }
    }
    __syncthreads();

    const int rowg = tid >> 4;
    const int colg = tid & 15;
    const int r0 = rowg * 4;
    const int c0 = colg * 8;

    float acc[4][8];
    #pragma unroll
    for (int i = 0; i < 4; ++i)
        #pragma unroll
        for (int j = 0; j < 8; ++j) acc[i][j] = 0.f;

    const float* Wb = W + (size_t)h * F_ * F_ + c0;
    #pragma unroll 4
    for (int f = 0; f < F_; ++f) {
        const float4 w0 = *reinterpret_cast<const float4*>(Wb + (size_t)f * F_);
        const float4 w1 = *reinterpret_cast<const float4*>(Wb + (size_t)f * F_ + 4);
        float a[4];
        #pragma unroll
        for (int i = 0; i < 4; ++i) a[i] = xs[r0 + i][f];
        #pragma unroll
        for (int i = 0; i < 4; ++i) {
            acc[i][0] += a[i] * w0.x; acc[i][1] += a[i] * w0.y;
            acc[i][2] += a[i] * w0.z; acc[i][3] += a[i] * w0.w;
            acc[i][4] += a[i] * w1.x; acc[i][5] += a[i] * w1.y;
            acc[i][6] += a[i] * w1.z; acc[i][7] += a[i] * w1.w;
        }
    }

    ushort_t hiv[4][8], lov[4][8];
    #pragma unroll
    for (int i = 0; i < 4; ++i)
        #pragma unroll
        for (int j = 0; j < 8; ++j) {
            float v = acc[i][j];
            _Float16 hh = (_Float16)v;                 // RTN
            _Float16 ll = (_Float16)(v - (float)hh);   // residual
            hiv[i][j] = __builtin_bit_cast(ushort_t, hh);
            lov[i][j] = __builtin_bit_cast(ushort_t, ll);
        }

    const size_t rowbase = (((size_t)h * T_ + t) * N_ + n0);
    #pragma unroll
    for (int i = 0; i < 4; ++i) {
        uint4 hv = *reinterpret_cast<uint4*>(&hiv[i][0]);
        uint4 lv = *reinterpret_cast<uint4*>(&lov[i][0]);
        *reinterpret_cast<uint4*>(th_hi + (rowbase + r0 + i) * F_ + c0) = hv;
        *reinterpret_cast<uint4*>(th_lo + (rowbase + r0 + i) * F_ + c0) = lv;
    }

    // transposed chunked hi copy: [h][t][nc][g][32]
    {
        const int nc = (n0 + r0) >> 5;
        const int nin = r0 & 31;
        ushort_t* base = th_hiT + ((((size_t)h * T_ + t) * (N_ / 32) + nc) * F_) * 32;
        #pragma unroll
        for (int j = 0; j < 8; ++j) {
            u32 p0 = (u32)hiv[0][j] | ((u32)hiv[1][j] << 16);
            u32 p1 = (u32)hiv[2][j] | ((u32)hiv[3][j] << 16);
            u32* dst = reinterpret_cast<u32*>(base + (size_t)(c0 + j) * 32 + nin);
            dst[0] = p0;
            dst[1] = p1;
        }
    }
}

// ---------------------------------------------------------------------------
// Kernel 2: MFMA flash attention, S^T = K*Q^T, fp16 2-term hi/lo scores,
// software-pipelined: scores(tile mt+1) overlaps softmax+PV(tile mt).
// 3-deep LDS buffers, T14 reg staging 2 tiles ahead, T13 defer-rescale.
// grid = 512 = (h,t,qtile); block = 256 (4 waves x 32 q-cols each).
// ---------------------------------------------------------------------------
__global__ __launch_bounds__(256, 2) void k_attn(const ushort_t* __restrict__ th_hi,
                                                 const ushort_t* __restrict__ th_lo,
                                                 const ushort_t* __restrict__ th_hiT,
                                                 float* __restrict__ s_part) {
    __shared__ ushort_t kh[3][32][128];
    __shared__ ushort_t vt[3][64][72];

    const int tid = threadIdx.x;
    const int lane = tid & 63;
    const int w = tid >> 6;
    const int l31 = lane & 31;
    const int h5 = lane >> 5;

    // XCD-grouping swizzle: 16 q-siblings (same h,t) land on one XCD
    const int vid = ((blockIdx.x & 7) << 6) | (blockIdx.x >> 3);
    const int h = vid >> 7;
    const int t = (vid >> 4) & 7;
    const int qt = vid & 15;
    const int q0 = qt * 128 + w * 32;

    const size_t ht = (size_t)h * T_ + t;
    const ushort_t* Khi_g = th_hi + ht * (N_ * F_);
    const ushort_t* VT_g  = th_hiT + ht * ((N_ / 32) * F_ * 32);
    const ushort_t* Qhi_g = th_hi + ((size_t)h * T_ + (T_ - 1)) * (N_ * F_);
    const ushort_t* Qlo_g = th_lo + ((size_t)h * T_ + (T_ - 1)) * (N_ * F_);

    // Q fragments: lane -> q = q0+l31, f = ks*16 + h5*8 + j
    f16x8 qh[8], ql[8];
    {
        const ushort_t* qrh = Qhi_g + (size_t)(q0 + l31) * F_ + h5 * 8;
        const ushort_t* qrl = Qlo_g + (size_t)(q0 + l31) * F_ + h5 * 8;
        #pragma unroll
        for (int ks = 0; ks < 8; ++ks) {
            qh[ks] = *reinterpret_cast<const f16x8*>(qrh + ks * 16);
            ql[ks] = *reinterpret_cast<const f16x8*>(qrl + ks * 16);
        }
    }

    const int sm = tid >> 3;            // K staging row 0..31
    const int sfc = tid & 7;            // K staging 16-elem f chunk
    const int ssx = sm & 15;
    const int sg = tid >> 1;            // V staging g-row 0..127
    const int smh = (tid & 1) * 16;     // V staging m half

    f32x16 o2[4];
    #pragma unroll
    for (int gs = 0; gs < 4; ++gs)
        #pragma unroll
        for (int r = 0; r < 16; ++r) o2[gs][r] = 0.f;

    float m_run = -3e38f, l_run = 0.f;
    const float CL2 = 1.4426950408889634f;

    uint4 sa0, sa1, sv0, sv1;   // T14 staging registers

    auto stage_load = [&](int mt) {
        const size_t grow = (size_t)(mt * 32 + sm) * F_ + sfc * 16;
        sa0 = *reinterpret_cast<const uint4*>(Khi_g + grow);
        sa1 = *reinterpret_cast<const uint4*>(Khi_g + grow + 8);
        const ushort_t* vsrc = VT_g + (size_t)mt * (F_ * 32) + (size_t)sg * 32 + smh;
        sv0 = *reinterpret_cast<const uint4*>(vsrc);
        sv1 = *reinterpret_cast<const uint4*>(vsrc + 8);
    };
    auto stage_write = [&](int buf) {
        *reinterpret_cast<uint4*>(&kh[buf][sm][((sfc * 2 + 0) ^ ssx) * 8]) = sa0;
        *reinterpret_cast<uint4*>(&kh[buf][sm][((sfc * 2 + 1) ^ ssx) * 8]) = sa1;
        ushort_t* vdst = &vt[buf][sg >> 1][(sg & 1) * 32 + smh];
        *reinterpret_cast<uint4*>(vdst) = sv0;
        *reinterpret_cast<uint4*>(vdst + 8) = sv1;
    };
    auto scores = [&](int buf) -> f32x16 {
        f32x16 S;
        #pragma unroll
        for (int r = 0; r < 16; ++r) S[r] = 0.f;
        __builtin_amdgcn_s_setprio(1);
        #pragma unroll
        for (int ks = 0; ks < 8; ++ks) {
            const f16x8 ah = *reinterpret_cast<const f16x8*>(
                &kh[buf][l31][((ks * 2 + h5) ^ (l31 & 15)) * 8]);
            S = __builtin_amdgcn_mfma_f32_32x32x16_f16(ah, qh[ks], S, 0, 0, 0);
            S = __builtin_amdgcn_mfma_f32_32x32x16_f16(ah, ql[ks], S, 0, 0, 0);
        }
        __builtin_amdgcn_s_setprio(0);
        return S;
    };
    auto softmax_pv = [&](f32x16& S, int buf) {
        // row-max tree (per-lane q column) + half-wave combine
        float a0 = fmaxf(S[0], S[1]),  a1 = fmaxf(S[2], S[3]);
        float a2 = fmaxf(S[4], S[5]),  a3 = fmaxf(S[6], S[7]);
        float a4 = fmaxf(S[8], S[9]),  a5 = fmaxf(S[10], S[11]);
        float a6 = fmaxf(S[12], S[13]), a7 = fmaxf(S[14], S[15]);
        float b0 = fmaxf(a0, a1), b1 = fmaxf(a2, a3);
        float b2 = fmaxf(a4, a5), b3 = fmaxf(a6, a7);
        float tm = fmaxf(fmaxf(b0, b1), fmaxf(b2, b3));
        tm = fmaxf(tm, __shfl_xor(tm, 32));

        // T13: defer rescale unless max grew beyond threshold
        if (__any(tm > m_run + 8.f)) {
            const float Mn = fmaxf(m_run, tm);
            const float alpha = exp2f((m_run - Mn) * CL2);
            l_run *= alpha;
            #pragma unroll
            for (int gs = 0; gs < 4; ++gs)
                #pragma unroll
                for (int r = 0; r < 16; ++r) o2[gs][r] *= alpha;
            m_run = Mn;
        }
        const float mc = m_run * CL2;
        float p[16];
        #pragma unroll
        for (int r = 0; r < 16; ++r) p[r] = exp2f(S[r] * CL2 - mc);
        float ts = (((p[0] + p[1]) + (p[2] + p[3])) + ((p[4] + p[5]) + (p[6] + p[7])))
                 + (((p[8] + p[9]) + (p[10] + p[11])) + ((p[12] + p[13]) + (p[14] + p[15])));
        ts += __shfl_xor(ts, 32);
        l_run += ts;

        // pack P^T fragments in-register (cvt_pkrtz + half-wave swap)
        u32 pk[8], xk[8];
        #pragma unroll
        for (int c = 0; c < 8; ++c) {
            auto r2 = __builtin_amdgcn_cvt_pkrtz(p[2 * c], p[2 * c + 1]);
            pk[c] = __builtin_bit_cast(u32, r2);
        }
        #pragma unroll
        for (int c = 0; c < 8; ++c) xk[c] = (u32)__shfl_xor((int)pk[c], 32);

        u32x4 t0, t1;
        t0.x = h5 ? xk[2] : pk[0];
        t0.y = h5 ? xk[3] : pk[1];
        t0.z = h5 ? pk[2] : xk[0];
        t0.w = h5 ? pk[3] : xk[1];
        t1.x = h5 ? xk[6] : pk[4];
        t1.y = h5 ? xk[7] : pk[5];
        t1.z = h5 ? pk[6] : xk[4];
        t1.w = h5 ? pk[7] : xk[5];
        f16x8 pb0 = __builtin_bit_cast(f16x8, t0);
        f16x8 pb1 = __builtin_bit_cast(f16x8, t1);

        __builtin_amdgcn_s_setprio(1);
        #pragma unroll
        for (int gs = 0; gs < 4; ++gs) {
            const int g = gs * 32 + l31;
            const ushort_t* vrow = &vt[buf][g >> 1][(g & 1) * 32];
            f16x8 v0 = *reinterpret_cast<const f16x8*>(vrow + h5 * 8);
            f16x8 v1 = *reinterpret_cast<const f16x8*>(vrow + 16 + h5 * 8);
            o2[gs] = __builtin_amdgcn_mfma_f32_32x32x16_f16(v0, pb0, o2[gs], 0, 0, 0);
            o2[gs] = __builtin_amdgcn_mfma_f32_32x32x16_f16(v1, pb1, o2[gs], 0, 0, 0);
        }
        __builtin_amdgcn_s_setprio(0);
    };

    // prologue: stage tiles 0 and 1, compute scores(tile 0)
    stage_load(0); stage_write(0);
    stage_load(1); stage_write(1);
    __syncthreads();
    f32x16 S_A = scores(0);

    int cur = 0, nxt = 1, stg = 2;
    for (int mt = 0; mt < NT_ - 1; ++mt) {
        if (mt < NT_ - 2) stage_load(mt + 2);     // issue-early (T14)
        f32x16 S_B = scores(nxt);                 // MFMA for next tile...
        softmax_pv(S_A, cur);                     // ...overlaps softmax+PV of this one
        if (mt < NT_ - 2) stage_write(stg);       // write-late (T14)
        __syncthreads();
        S_A = S_B;
        const int tmp = cur; cur = nxt; nxt = stg; stg = tmp;
    }
    softmax_pv(S_A, cur);   // final tile (in buffer cur = 63 % 3 = 0)

    // epilogue: normalize and scatter-store out^T
    const float inv = 1.f / l_run;
    float* dst = s_part + (ht * N_ + (q0 + l31)) * F_;
    #pragma unroll
    for (int gs = 0; gs < 4; ++gs)
        #pragma unroll
        for (int r = 0; r < 16; ++r) {
            const int g = gs * 32 + (r & 3) + 8 * (r >> 2) + 4 * h5;
            dst[g] = o2[gs][r] * inv;
        }
}

// ---------------------------------------------------------------------------
// Kernel 3: out[n,g] = mean_h elu( (1/T) * sum_t s_part[h][t][n][g] )
// ---------------------------------------------------------------------------
__global__ __launch_bounds__(256) void k_out(const float* __restrict__ s_part,
                                             float* __restrict__ out) {
    const int i = blockIdx.x * blockDim.x + threadIdx.x;
    if (i >= (N_ * F_) / 4) return;
    const float4* sp = reinterpret_cast<const float4*>(s_part);
    float4 acc = {0.f, 0.f, 0.f, 0.f};
    const float invT = 1.f / (float)T_;
    #pragma unroll
    for (int h = 0; h < H_; ++h) {
        float4 hs = {0.f, 0.f, 0.f, 0.f};
        #pragma unroll
        for (int t = 0; t < T_; ++t) {
            float4 v = sp[(size_t)(h * T_ + t) * (N_ * F_ / 4) + i];
            hs.x += v.x; hs.y += v.y; hs.z += v.z; hs.w += v.w;
        }
        float ex = hs.x * invT, ey = hs.y * invT, ez = hs.z * invT, ew = hs.w * invT;
        acc.x += (ex > 0.f) ? ex : (expf(ex) - 1.f);
        acc.y += (ey > 0.f) ? ey : (expf(ey) - 1.f);
        acc.z += (ez > 0.f) ? ez : (expf(ez) - 1.f);
        acc.w += (ew > 0.f) ? ew : (expf(ew) - 1.f);
    }
    const float q = 1.f / (float)H_;
    float4 r = {acc.x * q, acc.y * q, acc.z * q, acc.w * q};
    reinterpret_cast<float4*>(out)[i] = r;
}

extern "C" void kernel_launch(void* const* d_in, const int* in_sizes, int n_in,
                              void* d_out, int out_size, void* d_ws, size_t ws_size,
                              hipStream_t stream) {
    const float* x = (const float*)d_in[0];   // (T, N, F)
    const float* W = (const float*)d_in[1];   // (H, F, F)
    float* out = (float*)d_out;               // (N, F)

    // ws layout: th_hi 16MB | th_lo 16MB | th_hiT 16MB | s_part 32MB  (80MB)
    const size_t TH_ELEMS = (size_t)H_ * T_ * N_ * F_;   // 8,388,608
    ushort_t* th_hi = (ushort_t*)d_ws;
    ushort_t* th_lo = th_hi + TH_ELEMS;
    ushort_t* th_hiT = th_lo + TH_ELEMS;
    float* s_part = (float*)(th_hiT + TH_ELEMS);

    k_th<<<H_ * T_ * (N_ / 64), 256, 0, stream>>>(x, W, th_hi, th_lo, th_hiT);
    k_attn<<<512, 256, 0, stream>>>(th_hi, th_lo, th_hiT, s_part);
    k_out<<<(N_ * F_ / 4 + 255) / 256, 256, 0, stream>>>(s_part, out);
}